// Round 17
// baseline (213.167 us; speedup 1.0000x reference)
//
#include <hip/hip_runtime.h>
#include <math.h>

#define B_ROWS 4096
#define NSTR 4
#define C_DIM 4096
#define NC 16384      // NSTR*C_DIM
#define NC4 4096      // NC/4 (float4 per batch row)
#define C4 1024       // C_DIM/4 (float4 per stream)

// clang's amdgcn builtins (cvt_pkrtz "V2hff", fdot2 "fV2hV2hfb") use __fp16
// vectors -- NOT _Float16 vectors. Use __fp16 throughout.
typedef __fp16 half2_t __attribute__((ext_vector_type(2)));
typedef __fp16 half4_t __attribute__((ext_vector_type(4)));
typedef __fp16 half8_t __attribute__((ext_vector_type(8)));

// ---------------------------------------------------------------------------
// Kernel 0: repack phi into one contiguous f16 buffer [24][16384].
// Row order: [pre0..3, post0..3, res0..15]. f32->f16 via cvt_pkrtz.
// ---------------------------------------------------------------------------
__global__ void repack16_kernel(
    const float4* __restrict__ pre4,
    const float4* __restrict__ post4,
    const float4* __restrict__ res4,
    half4_t* __restrict__ ws16)
{
    const int idx = blockIdx.x * blockDim.x + threadIdx.x;   // 0 .. 24*4096-1
    if (idx >= 24 * NC4) return;
    const int row = idx / NC4;
    const int k4  = idx % NC4;
    float4 v;
    if (row < 4)        v = pre4[row * NC4 + k4];
    else if (row < 8)   v = post4[(row - 4) * NC4 + k4];
    else                v = res4[(row - 8) * NC4 + k4];
    const half2_t lo = __builtin_amdgcn_cvt_pkrtz(v.x, v.y);
    const half2_t hi = __builtin_amdgcn_cvt_pkrtz(v.z, v.w);
    ws16[idx] = __builtin_shufflevector(lo, hi, 0, 1, 2, 3);
}

// ---------------------------------------------------------------------------
// FUSED kernel: 4 batch rows per block, 1024 threads (16 waves), 1 block/CU.
// x is read from HBM exactly ONCE (R16 post-mortem: out_kernel's 256MB
// re-read of x was ~82us of pure traffic; one row = 32KB f16 -> 4 rows fit
// in 128KB LDS, m201 precedent for 128KiB static LDS).
//
// Phase A: reg-stage x -> cvt_pkrtz -> f16 LDS; ssq accumulated in f32.
//          wave w stages quarter (w&3) of row (w>>2).
// Phase B: dots. wave w = phi-triple g=(w&7) x K-half h=(w>>3); computes
//          dots of phi rows 3g..3g+2 against ALL 4 rows via fdot2
//          (2 MACs/instr, R16-proven). 48 fdot2/iter, 16 iters.
// Phase C: threads 0-3: rms factor, softmax, 2*sigmoid, Sinkhorn(20) -> LDS.
// Phase D: out. wave w = row (w>>2) x channel-quarter (w&3): x_agg from
//          LDS f16, cross-wave RMS reduce, fused mix + coalesced writes.
// HBM: 256MB read + 256MB write (was 768MB across 3 kernels).
// phi: 768KB data, 768MB L2 traffic (L2-resident per XCD).
// ---------------------------------------------------------------------------
__global__ __launch_bounds__(1024, 4) void fused_kernel(
    const float* __restrict__ x,
    const __fp16* __restrict__ phi16,    // [24][16384] f16
    const float* __restrict__ w,
    const float* __restrict__ b_pre,
    const float* __restrict__ b_post,
    const float* __restrict__ b_res,
    const float* __restrict__ alpha_pre,
    const float* __restrict__ alpha_post,
    const float* __restrict__ alpha_res,
    float* __restrict__ out)
{
    __shared__ __fp16 xh[4][16384];      // 128 KB: 4 rows of x in f16
    __shared__ float  red[8][2][4][3];   // dots: [g][h][row][j]
    __shared__ float  redss[4][4];       // ssq partials [row][quarter]
    __shared__ float  params_s[4][24];   // per-row Hpre/Hpost/M
    __shared__ float  redo[4][4];        // x_agg ssq partials [row][quarter]

    const int tid  = threadIdx.x;
    const int wave = tid >> 6;           // 0..15
    const int lane = tid & 63;
    const int b0   = blockIdx.x * 4;

    const float4* __restrict__ x4 = reinterpret_cast<const float4*>(x);

    // ================= Phase A: stage x -> f16 LDS, ssq f32 ================
    {
        const int rw = wave >> 2;        // row 0..3
        const int q  = wave & 3;         // quarter of the row
        const float4* src = x4 + (size_t)(b0 + rw) * NC4 + q * 1024 + lane * 2;
        __fp16* dst = &xh[rw][q * 4096 + lane * 8];
        float ssq = 0.f;
#pragma unroll
        for (int i = 0; i < 8; ++i) {
            const float4 a = src[i * 128];
            const float4 b = src[i * 128 + 1];
            ssq += a.x*a.x + a.y*a.y + a.z*a.z + a.w*a.w;
            ssq += b.x*b.x + b.y*b.y + b.z*b.z + b.w*b.w;
            const half2_t h0 = __builtin_amdgcn_cvt_pkrtz(a.x, a.y);
            const half2_t h1 = __builtin_amdgcn_cvt_pkrtz(a.z, a.w);
            const half2_t h2 = __builtin_amdgcn_cvt_pkrtz(b.x, b.y);
            const half2_t h3 = __builtin_amdgcn_cvt_pkrtz(b.z, b.w);
            const half4_t lo = __builtin_shufflevector(h0, h1, 0, 1, 2, 3);
            const half4_t hi = __builtin_shufflevector(h2, h3, 0, 1, 2, 3);
            *reinterpret_cast<half8_t*>(dst + i * 512) =
                __builtin_shufflevector(lo, hi, 0, 1, 2, 3, 4, 5, 6, 7);
        }
#pragma unroll
        for (int off = 32; off > 0; off >>= 1)
            ssq += __shfl_xor(ssq, off, 64);
        if (lane == 0) redss[rw][q] = ssq;
    }
    __syncthreads();

    // ================= Phase B: dots via fdot2 ==============================
    {
        const int g = wave & 7;          // phi triple: rows 3g..3g+2
        const int h = wave >> 3;         // K-half
        const __fp16* pb = phi16 + (size_t)(3 * g) * NC + h * 8192 + lane * 8;

        float acc[4][3];
#pragma unroll
        for (int r = 0; r < 4; ++r)
#pragma unroll
            for (int j = 0; j < 3; ++j) acc[r][j] = 0.f;

#pragma unroll 2
        for (int i = 0; i < 16; ++i) {
            const int off = i * 512;
            half8_t pv[3];
            pv[0] = *reinterpret_cast<const half8_t*>(pb + off);
            pv[1] = *reinterpret_cast<const half8_t*>(pb + NC + off);
            pv[2] = *reinterpret_cast<const half8_t*>(pb + 2 * NC + off);
            half2_t ps[3][4];
#pragma unroll
            for (int j = 0; j < 3; ++j) {
                ps[j][0] = __builtin_shufflevector(pv[j], pv[j], 0, 1);
                ps[j][1] = __builtin_shufflevector(pv[j], pv[j], 2, 3);
                ps[j][2] = __builtin_shufflevector(pv[j], pv[j], 4, 5);
                ps[j][3] = __builtin_shufflevector(pv[j], pv[j], 6, 7);
            }
#pragma unroll
            for (int r = 0; r < 4; ++r) {
                const half8_t xv = *reinterpret_cast<const half8_t*>(
                    &xh[r][h * 8192 + off + lane * 8]);
                const half2_t x0 = __builtin_shufflevector(xv, xv, 0, 1);
                const half2_t x1 = __builtin_shufflevector(xv, xv, 2, 3);
                const half2_t x2 = __builtin_shufflevector(xv, xv, 4, 5);
                const half2_t x3 = __builtin_shufflevector(xv, xv, 6, 7);
#pragma unroll
                for (int j = 0; j < 3; ++j) {
                    float a = acc[r][j];
                    a = __builtin_amdgcn_fdot2(x0, ps[j][0], a, false);
                    a = __builtin_amdgcn_fdot2(x1, ps[j][1], a, false);
                    a = __builtin_amdgcn_fdot2(x2, ps[j][2], a, false);
                    a = __builtin_amdgcn_fdot2(x3, ps[j][3], a, false);
                    acc[r][j] = a;
                }
            }
        }

#pragma unroll
        for (int r = 0; r < 4; ++r)
#pragma unroll
            for (int j = 0; j < 3; ++j) {
                float v = acc[r][j];
#pragma unroll
                for (int off = 32; off > 0; off >>= 1)
                    v += __shfl_xor(v, off, 64);
                acc[r][j] = v;
            }
        if (lane == 0) {
#pragma unroll
            for (int r = 0; r < 4; ++r)
#pragma unroll
                for (int j = 0; j < 3; ++j)
                    red[g][h][r][j] = acc[r][j];
        }
    }
    __syncthreads();

    // ================= Phase C: finalize (threads 0..3) ====================
    if (tid < 4) {
        const int row = tid;
        float d[24];
#pragma unroll
        for (int o = 0; o < 24; ++o)
            d[o] = red[o / 3][0][row][o % 3] + red[o / 3][1][row][o % 3];
        const float ssq = redss[row][0] + redss[row][1]
                        + redss[row][2] + redss[row][3];
        const float inv_rms = rsqrtf(ssq * (1.f / (float)NC) + 1e-8f);
        const float ap  = alpha_pre[0];
        const float apo = alpha_post[0];
        const float ar  = alpha_res[0];

        // softmax(h_pre)
        float hp[4];
        float mx = -1e30f;
#pragma unroll
        for (int j = 0; j < 4; ++j) {
            hp[j] = ap * d[j] * inv_rms + b_pre[j];
            mx = fmaxf(mx, hp[j]);
        }
        float e[4], s = 0.f;
#pragma unroll
        for (int j = 0; j < 4; ++j) { e[j] = expf(hp[j] - mx); s += e[j]; }
#pragma unroll
        for (int j = 0; j < 4; ++j) params_s[row][j] = e[j] / s;

        // 2*sigmoid(h_post)
#pragma unroll
        for (int j = 0; j < 4; ++j) {
            const float h = apo * d[4 + j] * inv_rms + b_post[j];
            params_s[row][4 + j] = 2.f / (1.f + expf(-h));
        }

        // Sinkhorn on exp(h_res)
        float M[16];
#pragma unroll
        for (int k = 0; k < 16; ++k)
            M[k] = expf(ar * d[8 + k] * inv_rms + b_res[k]);
        for (int it = 0; it < 20; ++it) {
#pragma unroll
            for (int i = 0; i < 4; ++i) {
                const float rs = M[i*4+0] + M[i*4+1] + M[i*4+2] + M[i*4+3] + 1e-8f;
#pragma unroll
                for (int j = 0; j < 4; ++j) M[i*4+j] = M[i*4+j] / rs;
            }
#pragma unroll
            for (int j = 0; j < 4; ++j) {
                const float cs = M[0*4+j] + M[1*4+j] + M[2*4+j] + M[3*4+j] + 1e-8f;
#pragma unroll
                for (int i = 0; i < 4; ++i) M[i*4+j] = M[i*4+j] / cs;
            }
        }
#pragma unroll
        for (int k = 0; k < 16; ++k) params_s[row][8 + k] = M[k];
    }
    __syncthreads();

    // ================= Phase D: aggregate, rmsnorm, mix, write =============
    {
        const int rw = wave >> 2;        // row
        const int q  = wave & 3;         // channel quarter
        float Hpre[4], Hpost[4], M[16];
#pragma unroll
        for (int j = 0; j < 4; ++j)  Hpre[j]  = params_s[rw][j];
#pragma unroll
        for (int j = 0; j < 4; ++j)  Hpost[j] = params_s[rw][4 + j];
#pragma unroll
        for (int k = 0; k < 16; ++k) M[k]     = params_s[rw][8 + k];

        const float4* __restrict__ w4 = reinterpret_cast<const float4*>(w);
        float4* __restrict__ out4 = reinterpret_cast<float4*>(out);
        const size_t obase = (size_t)(b0 + rw) * NC4;

        float4 xagg[4];
        float ssa = 0.f;
#pragma unroll
        for (int it = 0; it < 4; ++it) {
            const int cf = q * 256 + it * 64 + lane;   // float4-channel index
            float4 xn[4];
#pragma unroll
            for (int n = 0; n < 4; ++n) {
                const half4_t hv = *reinterpret_cast<const half4_t*>(
                    &xh[rw][n * 4096 + cf * 4]);
                xn[n].x = (float)hv[0]; xn[n].y = (float)hv[1];
                xn[n].z = (float)hv[2]; xn[n].w = (float)hv[3];
            }
            float4 a;
            a.x = Hpre[0]*xn[0].x + Hpre[1]*xn[1].x + Hpre[2]*xn[2].x + Hpre[3]*xn[3].x;
            a.y = Hpre[0]*xn[0].y + Hpre[1]*xn[1].y + Hpre[2]*xn[2].y + Hpre[3]*xn[3].y;
            a.z = Hpre[0]*xn[0].z + Hpre[1]*xn[1].z + Hpre[2]*xn[2].z + Hpre[3]*xn[3].z;
            a.w = Hpre[0]*xn[0].w + Hpre[1]*xn[1].w + Hpre[2]*xn[2].w + Hpre[3]*xn[3].w;
            xagg[it] = a;
            ssa += a.x*a.x + a.y*a.y + a.z*a.z + a.w*a.w;
        }
#pragma unroll
        for (int off = 32; off > 0; off >>= 1)
            ssa += __shfl_xor(ssa, off, 64);
        if (lane == 0) redo[rw][q] = ssa;
        __syncthreads();
        const float tot = redo[rw][0] + redo[rw][1] + redo[rw][2] + redo[rw][3];
        const float inv = rsqrtf(tot * (1.f / (float)C_DIM) + 1e-5f);

#pragma unroll
        for (int it = 0; it < 4; ++it) {
            const int cf = q * 256 + it * 64 + lane;
            const float4 wv = w4[cf];
            float4 y;
            y.x = xagg[it].x * inv * wv.x;
            y.y = xagg[it].y * inv * wv.y;
            y.z = xagg[it].z * inv * wv.z;
            y.w = xagg[it].w * inv * wv.w;

            float4 xn[4];
#pragma unroll
            for (int n = 0; n < 4; ++n) {
                const half4_t hv = *reinterpret_cast<const half4_t*>(
                    &xh[rw][n * 4096 + cf * 4]);
                xn[n].x = (float)hv[0]; xn[n].y = (float)hv[1];
                xn[n].z = (float)hv[2]; xn[n].w = (float)hv[3];
            }
#pragma unroll
            for (int i = 0; i < 4; ++i) {
                float4 o;
                o.x = Hpost[i]*y.x + M[i*4+0]*xn[0].x + M[i*4+1]*xn[1].x
                                   + M[i*4+2]*xn[2].x + M[i*4+3]*xn[3].x;
                o.y = Hpost[i]*y.y + M[i*4+0]*xn[0].y + M[i*4+1]*xn[1].y
                                   + M[i*4+2]*xn[2].y + M[i*4+3]*xn[3].y;
                o.z = Hpost[i]*y.z + M[i*4+0]*xn[0].z + M[i*4+1]*xn[1].z
                                   + M[i*4+2]*xn[2].z + M[i*4+3]*xn[3].z;
                o.w = Hpost[i]*y.w + M[i*4+0]*xn[0].w + M[i*4+1]*xn[1].w
                                   + M[i*4+2]*xn[2].w + M[i*4+3]*xn[3].w;
                out4[obase + (size_t)i * C4 + cf] = o;
            }
        }
    }
}

// ---------------------------------------------------------------------------
extern "C" void kernel_launch(void* const* d_in, const int* in_sizes, int n_in,
                              void* d_out, int out_size, void* d_ws, size_t ws_size,
                              hipStream_t stream) {
    const float* x        = (const float*)d_in[0];
    const float* w        = (const float*)d_in[1];
    const float* phi_pre  = (const float*)d_in[2];
    const float* phi_post = (const float*)d_in[3];
    const float* phi_res  = (const float*)d_in[4];
    const float* b_pre    = (const float*)d_in[5];
    const float* b_post   = (const float*)d_in[6];
    const float* b_res    = (const float*)d_in[7];
    const float* a_pre    = (const float*)d_in[8];
    const float* a_post   = (const float*)d_in[9];
    const float* a_res    = (const float*)d_in[10];
    float* out = (float*)d_out;

    half4_t* phi16 = (half4_t*)d_ws;     // [24][4096] half4 = 768 KB

    hipLaunchKernelGGL(repack16_kernel, dim3((24 * NC4 + 255) / 256), dim3(256), 0, stream,
                       (const float4*)phi_pre, (const float4*)phi_post,
                       (const float4*)phi_res, phi16);
    hipLaunchKernelGGL(fused_kernel, dim3(B_ROWS / 4), dim3(1024), 0, stream,
                       x, (const __fp16*)phi16, w,
                       b_pre, b_post, b_res, a_pre, a_post, a_res, out);
}